// Round 1
// baseline (1281.197 us; speedup 1.0000x reference)
//
#include <hip/hip_runtime.h>
#include <hip/hip_bf16.h>

#define NT    10
#define NN    2048   // n_neurons
#define CA3C  2048
#define SEQ   1024
#define SPARS 0.05f
#define LRC   0.01f

// ---------------- Phase A: hippo_input[s][n] = sum_t tok_spike*(1+0.5*pos_spike) ----
__global__ __launch_bounds__(256) void k_hippo(const int* __restrict__ tok,
        const float* __restrict__ sdr, const float* __restrict__ pos,
        float* __restrict__ hippo) {
    int s = blockIdx.x;
    int n = (blockIdx.y * 256 + threadIdx.x) * 4;
    const float* sp = sdr + (long)tok[s] * (NT * NN) + n;
    const float* pp = pos + (long)s * (NT * NN) + n;
    float a0 = 0.f, a1 = 0.f, a2 = 0.f, a3 = 0.f;
    #pragma unroll
    for (int t = 0; t < NT; ++t) {
        float4 sv = *(const float4*)(sp + t * NN);
        float4 pv = *(const float4*)(pp + t * NN);
        if (sv.x < SPARS) a0 += (pv.x < SPARS) ? 1.5f : 1.0f;
        if (sv.y < SPARS) a1 += (pv.y < SPARS) ? 1.5f : 1.0f;
        if (sv.z < SPARS) a2 += (pv.z < SPARS) ? 1.5f : 1.0f;
        if (sv.w < SPARS) a3 += (pv.w < SPARS) ? 1.5f : 1.0f;
    }
    *(float4*)(hippo + (long)s * NN + n) = make_float4(a0, a1, a2, a3);
}

// ---------------- Phase B: dots[s][c] = hippo[s] . w_hippo[c]  (fp32 tiled GEMM) ----
__global__ __launch_bounds__(256) void k_gemm(const float* __restrict__ A,
        const float* __restrict__ B, float* __restrict__ C) {
    __shared__ float As[32][68];   // [k][m], padded row stride 68 (16B aligned)
    __shared__ float Bs[32][68];   // [k][n]
    int tid = threadIdx.x;
    int tx = tid & 15, ty = tid >> 4;
    int m0 = blockIdx.y * 64, n0 = blockIdx.x * 64;
    int lr = tid >> 3;            // 0..31
    int lk = (tid & 7) * 4;       // 0..28
    float acc[4][4] = {};
    for (int k0 = 0; k0 < NN; k0 += 32) {
        float4 a0 = *(const float4*)(A + (m0 + lr) * NN + k0 + lk);
        float4 a1 = *(const float4*)(A + (m0 + lr + 32) * NN + k0 + lk);
        float4 b0 = *(const float4*)(B + (n0 + lr) * NN + k0 + lk);
        float4 b1 = *(const float4*)(B + (n0 + lr + 32) * NN + k0 + lk);
        __syncthreads();
        As[lk + 0][lr] = a0.x; As[lk + 1][lr] = a0.y; As[lk + 2][lr] = a0.z; As[lk + 3][lr] = a0.w;
        As[lk + 0][lr + 32] = a1.x; As[lk + 1][lr + 32] = a1.y; As[lk + 2][lr + 32] = a1.z; As[lk + 3][lr + 32] = a1.w;
        Bs[lk + 0][lr] = b0.x; Bs[lk + 1][lr] = b0.y; Bs[lk + 2][lr] = b0.z; Bs[lk + 3][lr] = b0.w;
        Bs[lk + 0][lr + 32] = b1.x; Bs[lk + 1][lr + 32] = b1.y; Bs[lk + 2][lr + 32] = b1.z; Bs[lk + 3][lr + 32] = b1.w;
        __syncthreads();
        #pragma unroll
        for (int k = 0; k < 32; ++k) {
            float4 av = *(const float4*)&As[k][ty * 4];
            float4 bv = *(const float4*)&Bs[k][tx * 4];
            float aa[4] = {av.x, av.y, av.z, av.w};
            float bb[4] = {bv.x, bv.y, bv.z, bv.w};
            #pragma unroll
            for (int i = 0; i < 4; ++i)
                #pragma unroll
                for (int j = 0; j < 4; ++j)
                    acc[i][j] = fmaf(aa[i], bb[j], acc[i][j]);
        }
    }
    #pragma unroll
    for (int i = 0; i < 4; ++i)
        *(float4*)(C + (long)(m0 + ty * 4 + i) * CA3C + n0 + tx * 4) =
            make_float4(acc[i][0], acc[i][1], acc[i][2], acc[i][3]);
}

// ---------------- Phase B2: fp64 re-check of near-zero dots (sign safety) ----------
__global__ __launch_bounds__(256) void k_fixup(const float* __restrict__ hippo,
        const float* __restrict__ w, float* __restrict__ dots) {
    long i = (long)blockIdx.x * 256 + threadIdx.x;
    float d = dots[i];
    if (fabsf(d) < 1e-3f) {
        int s = (int)(i / CA3C), c = (int)(i % CA3C);
        const float* hr = hippo + (long)s * NN;
        const float* wr = w + (long)c * NN;
        double acc = 0.0;
        for (int n = 0; n < NN; ++n) acc += (double)hr[n] * (double)wr[n];
        dots[i] = (acc > 0.0) ? 1.0f : -1.0f;   // only the sign is consumed
    }
}

// ---------------- Phase C0: pack pre bits [s][64 words] + per-step popcount --------
__global__ __launch_bounds__(64) void k_packpre(const float* __restrict__ dots,
        unsigned* __restrict__ pre_bits, float* __restrict__ pre_popf) {
    int s = blockIdx.x;
    int lane = threadIdx.x;                    // 0..63 -> word index
    const float* row = dots + (long)s * CA3C + lane * 32;
    unsigned m = 0;
    #pragma unroll
    for (int j = 0; j < 32; ++j) m |= (row[j] > 0.0f ? 1u : 0u) << j;
    pre_bits[s * 64 + lane] = m;
    int pc = __popc(m);
    #pragma unroll
    for (int o = 1; o < 64; o <<= 1) pc += __shfl_xor(pc, o, 64);
    if (lane == 0) pre_popf[s] = (float)pc;
}

// ---------------- Phase C1: pack post bits transposed [r][32 words over steps] -----
__global__ __launch_bounds__(256) void k_packpost(const float* __restrict__ dots,
        unsigned* __restrict__ postT) {
    int r = blockIdx.x * 256 + threadIdx.x;    // 0..2047
    #pragma unroll 1
    for (int wi = 0; wi < 32; ++wi) {
        unsigned m = 0;
        int jmax = (wi == 31) ? 31 : 32;       // steps s = wi*32+j, s <= 1022
        for (int j = 0; j < jmax; ++j) {
            int s = wi * 32 + j;
            m |= (dots[(long)(s + 1) * CA3C + r] > 0.0f ? 1u : 0u) << j;
        }
        postT[r * 32 + wi] = m;
    }
}

// ---------------- Phase D: per-row sequential Hebbian scan (1 wave = 1 row) --------
// Row invariant: after every step each row has norm <= 1, so steps with post[r]=0
// are bitwise no-ops. Deferred scale: W_r = alpha * V_r, nu = ||W_r||^2 tracked
// incrementally; division folds into alpha.
__global__ __launch_bounds__(256) void k_scan(const float* __restrict__ W0,
        const unsigned* __restrict__ pre_bits, const float* __restrict__ pre_popf,
        const unsigned* __restrict__ postT, float* __restrict__ Wout) {
    int r = (blockIdx.x * 256 + threadIdx.x) >> 6;   // wave id = row
    int lane = threadIdx.x & 63;
    const float* src = W0 + (long)r * CA3C + lane * 32;
    float V[32];
    #pragma unroll
    for (int j = 0; j < 32; ++j) V[j] = src[j];
    float nu = 0.f;
    #pragma unroll
    for (int j = 0; j < 32; ++j) nu = fmaf(V[j], V[j], nu);
    #pragma unroll
    for (int o = 1; o < 64; o <<= 1) nu += __shfl_xor(nu, o, 64);
    float alpha = 1.f, inv_alpha = 1.f;
    if (nu > 1.f) { float nrm = sqrtf(nu); alpha /= nrm; inv_alpha = 1.f / alpha; nu = 1.f; }

    unsigned pw = 0;
    unsigned mnext = pre_bits[lane];                 // prefetch step 0
    float popnext = pre_popf[0];
    for (int s = 0; s < SEQ - 1; ++s) {
        unsigned m = mnext;
        float pop = popnext;
        if (s + 1 < SEQ - 1) {
            mnext = pre_bits[(s + 1) * 64 + lane];
            popnext = pre_popf[s + 1];
        }
        if ((s & 31) == 0) pw = __builtin_amdgcn_readfirstlane(postT[r * 32 + (s >> 5)]);
        if ((pw >> (s & 31)) & 1u) {
            float c = LRC * inv_alpha;
            float dot = 0.f;
            #pragma unroll
            for (int j = 0; j < 32; ++j) {
                float f = (float)((m >> j) & 1u);
                dot = fmaf(f, V[j], dot);            // uses pre-update V[j]
                V[j] = fmaf(f, c, V[j]);
            }
            #pragma unroll
            for (int o = 1; o < 64; o <<= 1) dot += __shfl_xor(dot, o, 64);
            nu = fmaf(2.f * LRC, alpha * dot, fmaf(LRC * LRC, pop, nu));
            if (nu > 1.f) {
                float nrm = sqrtf(nu);
                alpha = alpha / nrm;
                inv_alpha = 1.f / alpha;
                nu = 1.f;
            }
            if (alpha < 1e-6f) {                     // re-materialize to avoid overflow
                #pragma unroll
                for (int j = 0; j < 32; ++j) V[j] *= alpha;
                alpha = 1.f; inv_alpha = 1.f;
            }
        }
    }
    float* dst = Wout + (long)r * CA3C + lane * 32;
    #pragma unroll
    for (int j = 0; j < 32; ++j) dst[j] = alpha * V[j];
}

extern "C" void kernel_launch(void* const* d_in, const int* in_sizes, int n_in,
                              void* d_out, int out_size, void* d_ws, size_t ws_size,
                              hipStream_t stream) {
    const int*   tok     = (const int*)d_in[0];
    const float* sdr     = (const float*)d_in[1];
    const float* pos     = (const float*)d_in[2];
    const float* w_hippo = (const float*)d_in[3];
    const float* assoc   = (const float*)d_in[4];
    float* out = (float*)d_out;

    char* ws = (char*)d_ws;
    float*    hippo    = (float*)(ws);                     // 8 MB
    float*    dots     = (float*)(ws + 8388608);           // 8 MB
    unsigned* pre_bits = (unsigned*)(ws + 16777216);       // 256 KB
    unsigned* postT    = (unsigned*)(ws + 17039360);       // 256 KB
    float*    pre_popf = (float*)(ws + 17301504);          // 4 KB

    k_hippo   <<<dim3(SEQ, 2),            256, 0, stream>>>(tok, sdr, pos, hippo);
    k_gemm    <<<dim3(CA3C/64, SEQ/64),   256, 0, stream>>>(hippo, w_hippo, dots);
    k_fixup   <<<dim3((SEQ*CA3C)/256),    256, 0, stream>>>(hippo, w_hippo, dots);
    k_packpre <<<dim3(SEQ),                64, 0, stream>>>(dots, pre_bits, pre_popf);
    k_packpost<<<dim3(CA3C/256),          256, 0, stream>>>(dots, postT);
    k_scan    <<<dim3(CA3C*64/256),       256, 0, stream>>>(assoc, pre_bits, pre_popf, postT, out);
}

// Round 2
// 1263.671 us; speedup vs baseline: 1.0139x; 1.0139x over previous
//
#include <hip/hip_runtime.h>
#include <hip/hip_bf16.h>

#define NT    10
#define NN    2048   // n_neurons
#define CA3C  2048
#define SEQ   1024
#define SPARS 0.05f
#define LRC   0.01f

// ---------------- Phase A: hippo_input[s][n] = sum_t tok_spike*(1+0.5*pos_spike) ----
__global__ __launch_bounds__(256) void k_hippo(const int* __restrict__ tok,
        const float* __restrict__ sdr, const float* __restrict__ pos,
        float* __restrict__ hippo) {
    int s = blockIdx.x;
    int n = (blockIdx.y * 256 + threadIdx.x) * 4;
    const float* sp = sdr + (long)tok[s] * (NT * NN) + n;
    const float* pp = pos + (long)s * (NT * NN) + n;
    float a0 = 0.f, a1 = 0.f, a2 = 0.f, a3 = 0.f;
    #pragma unroll
    for (int t = 0; t < NT; ++t) {
        float4 sv = *(const float4*)(sp + t * NN);
        float4 pv = *(const float4*)(pp + t * NN);
        if (sv.x < SPARS) a0 += (pv.x < SPARS) ? 1.5f : 1.0f;
        if (sv.y < SPARS) a1 += (pv.y < SPARS) ? 1.5f : 1.0f;
        if (sv.z < SPARS) a2 += (pv.z < SPARS) ? 1.5f : 1.0f;
        if (sv.w < SPARS) a3 += (pv.w < SPARS) ? 1.5f : 1.0f;
    }
    *(float4*)(hippo + (long)s * NN + n) = make_float4(a0, a1, a2, a3);
}

// ---------------- Phase B: dots[s][c] = hippo[s] . w_hippo[c]  (fp32 tiled GEMM) ----
__global__ __launch_bounds__(256) void k_gemm(const float* __restrict__ A,
        const float* __restrict__ B, float* __restrict__ C) {
    __shared__ float As[32][68];   // [k][m], padded row stride 68 (16B aligned)
    __shared__ float Bs[32][68];   // [k][n]
    int tid = threadIdx.x;
    int tx = tid & 15, ty = tid >> 4;
    int m0 = blockIdx.y * 64, n0 = blockIdx.x * 64;
    int lr = tid >> 3;            // 0..31
    int lk = (tid & 7) * 4;       // 0..28
    float acc[4][4] = {};
    for (int k0 = 0; k0 < NN; k0 += 32) {
        float4 a0 = *(const float4*)(A + (m0 + lr) * NN + k0 + lk);
        float4 a1 = *(const float4*)(A + (m0 + lr + 32) * NN + k0 + lk);
        float4 b0 = *(const float4*)(B + (n0 + lr) * NN + k0 + lk);
        float4 b1 = *(const float4*)(B + (n0 + lr + 32) * NN + k0 + lk);
        __syncthreads();
        As[lk + 0][lr] = a0.x; As[lk + 1][lr] = a0.y; As[lk + 2][lr] = a0.z; As[lk + 3][lr] = a0.w;
        As[lk + 0][lr + 32] = a1.x; As[lk + 1][lr + 32] = a1.y; As[lk + 2][lr + 32] = a1.z; As[lk + 3][lr + 32] = a1.w;
        Bs[lk + 0][lr] = b0.x; Bs[lk + 1][lr] = b0.y; Bs[lk + 2][lr] = b0.z; Bs[lk + 3][lr] = b0.w;
        Bs[lk + 0][lr + 32] = b1.x; Bs[lk + 1][lr + 32] = b1.y; Bs[lk + 2][lr + 32] = b1.z; Bs[lk + 3][lr + 32] = b1.w;
        __syncthreads();
        #pragma unroll
        for (int k = 0; k < 32; ++k) {
            float4 av = *(const float4*)&As[k][ty * 4];
            float4 bv = *(const float4*)&Bs[k][tx * 4];
            float aa[4] = {av.x, av.y, av.z, av.w};
            float bb[4] = {bv.x, bv.y, bv.z, bv.w};
            #pragma unroll
            for (int i = 0; i < 4; ++i)
                #pragma unroll
                for (int j = 0; j < 4; ++j)
                    acc[i][j] = fmaf(aa[i], bb[j], acc[i][j]);
        }
    }
    #pragma unroll
    for (int i = 0; i < 4; ++i)
        *(float4*)(C + (long)(m0 + ty * 4 + i) * CA3C + n0 + tx * 4) =
            make_float4(acc[i][0], acc[i][1], acc[i][2], acc[i][3]);
}

// ---------------- Phase B2: fp64 re-check of near-zero dots (sign safety) ----------
__global__ __launch_bounds__(256) void k_fixup(const float* __restrict__ hippo,
        const float* __restrict__ w, float* __restrict__ dots) {
    long i = (long)blockIdx.x * 256 + threadIdx.x;
    float d = dots[i];
    if (fabsf(d) < 1e-3f) {
        int s = (int)(i / CA3C), c = (int)(i % CA3C);
        const float* hr = hippo + (long)s * NN;
        const float* wr = w + (long)c * NN;
        double acc = 0.0;
        for (int n = 0; n < NN; ++n) acc += (double)hr[n] * (double)wr[n];
        dots[i] = (acc > 0.0) ? 1.0f : -1.0f;   // only the sign is consumed
    }
}

// ---------------- Phase C0: pack pre bits [s][64 words] + per-step popcount --------
__global__ __launch_bounds__(64) void k_packpre(const float* __restrict__ dots,
        unsigned* __restrict__ pre_bits, float* __restrict__ pre_popf) {
    int s = blockIdx.x;
    int lane = threadIdx.x;                    // 0..63 -> word index
    const float* row = dots + (long)s * CA3C + lane * 32;
    unsigned m = 0;
    #pragma unroll
    for (int j = 0; j < 32; ++j) m |= (row[j] > 0.0f ? 1u : 0u) << j;
    pre_bits[s * 64 + lane] = m;
    int pc = __popc(m);
    #pragma unroll
    for (int o = 1; o < 64; o <<= 1) pc += __shfl_xor(pc, o, 64);
    if (lane == 0) pre_popf[s] = (float)pc;
}

// ---------------- Phase C1: pack post bits transposed [r][32 words over steps] -----
__global__ __launch_bounds__(256) void k_packpost(const float* __restrict__ dots,
        unsigned* __restrict__ postT) {
    int r = blockIdx.x * 256 + threadIdx.x;    // 0..2047
    #pragma unroll 1
    for (int wi = 0; wi < 32; ++wi) {
        unsigned m = 0;
        int jmax = (wi == 31) ? 31 : 32;       // steps s = wi*32+j, s <= 1022
        for (int j = 0; j < jmax; ++j) {
            int s = wi * 32 + j;
            m |= (dots[(long)(s + 1) * CA3C + r] > 0.0f ? 1u : 0u) << j;
        }
        postT[r * 32 + wi] = m;
    }
}

// ---------------- DPP-based full-wave (64 lane) sum; result broadcast via lane 63 ---
__device__ __forceinline__ float wave_sum64(float x) {
    #define DPPADD(ctrl, rmask) \
        x += __int_as_float(__builtin_amdgcn_update_dpp(0, __float_as_int(x), ctrl, rmask, 0xF, true))
    DPPADD(0xB1, 0xF);    // quad_perm [1,0,3,2]  (xor 1)
    DPPADD(0x4E, 0xF);    // quad_perm [2,3,0,1]  (xor 2)
    DPPADD(0x141, 0xF);   // row_half_mirror      (xor 4)
    DPPADD(0x140, 0xF);   // row_mirror           (xor 8)
    DPPADD(0x142, 0xA);   // row_bcast15 -> rows 1,3
    DPPADD(0x143, 0xC);   // row_bcast31 -> rows 2,3
    #undef DPPADD
    return __int_as_float(__builtin_amdgcn_readlane(__float_as_int(x), 63));
}

// ---------------- Phase D: per-row sequential Hebbian scan (1 wave = 1 row) --------
// W_r = alpha * V_r; nu = ||W_r||^2 tracked incrementally. Renorm is division-free:
// alpha *= rsqrt(nu), inv_alpha *= sqrt(nu) (pair drift ~512*2^-24, negligible).
__global__ __launch_bounds__(256) void k_scan(const float* __restrict__ W0,
        const unsigned* __restrict__ pre_bits, const float* __restrict__ pre_popf,
        const unsigned* __restrict__ postT, float* __restrict__ Wout) {
    int r = (blockIdx.x * 256 + threadIdx.x) >> 6;   // wave id = row
    int lane = threadIdx.x & 63;
    const float* src = W0 + (long)r * CA3C + lane * 32;
    float V[32];
    #pragma unroll
    for (int j = 0; j < 32; ++j) V[j] = src[j];
    float p0 = 0.f, p1 = 0.f, p2 = 0.f, p3 = 0.f;
    #pragma unroll
    for (int j = 0; j < 32; j += 4) {
        p0 = fmaf(V[j+0], V[j+0], p0);
        p1 = fmaf(V[j+1], V[j+1], p1);
        p2 = fmaf(V[j+2], V[j+2], p2);
        p3 = fmaf(V[j+3], V[j+3], p3);
    }
    float nu = wave_sum64((p0 + p1) + (p2 + p3));
    float alpha = 1.f, inv_alpha = 1.f;
    if (nu > 1.f) {
        alpha *= rsqrtf(nu); inv_alpha *= sqrtf(nu); nu = 1.f;
    }

    unsigned pw = 0;
    unsigned mnext = pre_bits[lane];                 // prefetch step 0
    float popnext = pre_popf[0];
    for (int s = 0; s < SEQ - 1; ++s) {
        unsigned m = mnext;
        float pop = popnext;
        if (s + 1 < SEQ - 1) {
            mnext = pre_bits[(s + 1) * 64 + lane];
            popnext = pre_popf[s + 1];
        }
        if ((s & 31) == 0) pw = __builtin_amdgcn_readfirstlane(postT[r * 32 + (s >> 5)]);
        if ((pw >> (s & 31)) & 1u) {
            float c = LRC * inv_alpha;
            float d0 = 0.f, d1 = 0.f, d2 = 0.f, d3 = 0.f;
            #pragma unroll
            for (int j = 0; j < 32; j += 4) {
                float f0 = (float)((m >> (j + 0)) & 1u);
                float f1 = (float)((m >> (j + 1)) & 1u);
                float f2 = (float)((m >> (j + 2)) & 1u);
                float f3 = (float)((m >> (j + 3)) & 1u);
                d0 = fmaf(f0, V[j+0], d0); V[j+0] = fmaf(f0, c, V[j+0]);
                d1 = fmaf(f1, V[j+1], d1); V[j+1] = fmaf(f1, c, V[j+1]);
                d2 = fmaf(f2, V[j+2], d2); V[j+2] = fmaf(f2, c, V[j+2]);
                d3 = fmaf(f3, V[j+3], d3); V[j+3] = fmaf(f3, c, V[j+3]);
            }
            float dot = wave_sum64((d0 + d1) + (d2 + d3));
            nu = fmaf(2.f * LRC, alpha * dot, fmaf(LRC * LRC, pop, nu));
            if (nu > 1.f) {
                alpha *= rsqrtf(nu);
                inv_alpha *= sqrtf(nu);
                nu = 1.f;
            }
            if (alpha < 1e-6f) {                     // re-materialize to avoid drift/overflow
                #pragma unroll
                for (int j = 0; j < 32; ++j) V[j] *= alpha;
                alpha = 1.f; inv_alpha = 1.f;
            }
        }
    }
    float* dst = Wout + (long)r * CA3C + lane * 32;
    #pragma unroll
    for (int j = 0; j < 32; ++j) dst[j] = alpha * V[j];
}

extern "C" void kernel_launch(void* const* d_in, const int* in_sizes, int n_in,
                              void* d_out, int out_size, void* d_ws, size_t ws_size,
                              hipStream_t stream) {
    const int*   tok     = (const int*)d_in[0];
    const float* sdr     = (const float*)d_in[1];
    const float* pos     = (const float*)d_in[2];
    const float* w_hippo = (const float*)d_in[3];
    const float* assoc   = (const float*)d_in[4];
    float* out = (float*)d_out;

    char* ws = (char*)d_ws;
    float*    hippo    = (float*)(ws);                     // 8 MB
    float*    dots     = (float*)(ws + 8388608);           // 8 MB
    unsigned* pre_bits = (unsigned*)(ws + 16777216);       // 256 KB
    unsigned* postT    = (unsigned*)(ws + 17039360);       // 256 KB
    float*    pre_popf = (float*)(ws + 17301504);          // 4 KB

    k_hippo   <<<dim3(SEQ, 2),            256, 0, stream>>>(tok, sdr, pos, hippo);
    k_gemm    <<<dim3(CA3C/64, SEQ/64),   256, 0, stream>>>(hippo, w_hippo, dots);
    k_fixup   <<<dim3((SEQ*CA3C)/256),    256, 0, stream>>>(hippo, w_hippo, dots);
    k_packpre <<<dim3(SEQ),                64, 0, stream>>>(dots, pre_bits, pre_popf);
    k_packpost<<<dim3(CA3C/256),          256, 0, stream>>>(dots, postT);
    k_scan    <<<dim3(CA3C*64/256),       256, 0, stream>>>(assoc, pre_bits, pre_popf, postT, out);
}

// Round 3
// 1258.477 us; speedup vs baseline: 1.0181x; 1.0041x over previous
//
#include <hip/hip_runtime.h>
#include <hip/hip_bf16.h>

#define NT    10
#define NN    2048   // n_neurons
#define CA3C  2048
#define SEQ   1024
#define SPARS 0.05f
#define LRC   0.01f

// ---------------- Phase A: hippo_input[s][n] = sum_t tok_spike*(1+0.5*pos_spike) ----
__global__ __launch_bounds__(256) void k_hippo(const int* __restrict__ tok,
        const float* __restrict__ sdr, const float* __restrict__ pos,
        float* __restrict__ hippo) {
    int s = blockIdx.x;
    int n = (blockIdx.y * 256 + threadIdx.x) * 4;
    const float* sp = sdr + (long)tok[s] * (NT * NN) + n;
    const float* pp = pos + (long)s * (NT * NN) + n;
    float a0 = 0.f, a1 = 0.f, a2 = 0.f, a3 = 0.f;
    #pragma unroll
    for (int t = 0; t < NT; ++t) {
        float4 sv = *(const float4*)(sp + t * NN);
        float4 pv = *(const float4*)(pp + t * NN);
        if (sv.x < SPARS) a0 += (pv.x < SPARS) ? 1.5f : 1.0f;
        if (sv.y < SPARS) a1 += (pv.y < SPARS) ? 1.5f : 1.0f;
        if (sv.z < SPARS) a2 += (pv.z < SPARS) ? 1.5f : 1.0f;
        if (sv.w < SPARS) a3 += (pv.w < SPARS) ? 1.5f : 1.0f;
    }
    *(float4*)(hippo + (long)s * NN + n) = make_float4(a0, a1, a2, a3);
}

// ---------------- Phase B: dots[s][c] = hippo[s] . w_hippo[c]  (fp32 tiled GEMM) ----
__global__ __launch_bounds__(256) void k_gemm(const float* __restrict__ A,
        const float* __restrict__ B, float* __restrict__ C) {
    __shared__ float As[32][68];   // [k][m], padded row stride 68 (16B aligned)
    __shared__ float Bs[32][68];   // [k][n]
    int tid = threadIdx.x;
    int tx = tid & 15, ty = tid >> 4;
    int m0 = blockIdx.y * 64, n0 = blockIdx.x * 64;
    int lr = tid >> 3;            // 0..31
    int lk = (tid & 7) * 4;       // 0..28
    float acc[4][4] = {};
    for (int k0 = 0; k0 < NN; k0 += 32) {
        float4 a0 = *(const float4*)(A + (m0 + lr) * NN + k0 + lk);
        float4 a1 = *(const float4*)(A + (m0 + lr + 32) * NN + k0 + lk);
        float4 b0 = *(const float4*)(B + (n0 + lr) * NN + k0 + lk);
        float4 b1 = *(const float4*)(B + (n0 + lr + 32) * NN + k0 + lk);
        __syncthreads();
        As[lk + 0][lr] = a0.x; As[lk + 1][lr] = a0.y; As[lk + 2][lr] = a0.z; As[lk + 3][lr] = a0.w;
        As[lk + 0][lr + 32] = a1.x; As[lk + 1][lr + 32] = a1.y; As[lk + 2][lr + 32] = a1.z; As[lk + 3][lr + 32] = a1.w;
        Bs[lk + 0][lr] = b0.x; Bs[lk + 1][lr] = b0.y; Bs[lk + 2][lr] = b0.z; Bs[lk + 3][lr] = b0.w;
        Bs[lk + 0][lr + 32] = b1.x; Bs[lk + 1][lr + 32] = b1.y; Bs[lk + 2][lr + 32] = b1.z; Bs[lk + 3][lr + 32] = b1.w;
        __syncthreads();
        #pragma unroll
        for (int k = 0; k < 32; ++k) {
            float4 av = *(const float4*)&As[k][ty * 4];
            float4 bv = *(const float4*)&Bs[k][tx * 4];
            float aa[4] = {av.x, av.y, av.z, av.w};
            float bb[4] = {bv.x, bv.y, bv.z, bv.w};
            #pragma unroll
            for (int i = 0; i < 4; ++i)
                #pragma unroll
                for (int j = 0; j < 4; ++j)
                    acc[i][j] = fmaf(aa[i], bb[j], acc[i][j]);
        }
    }
    #pragma unroll
    for (int i = 0; i < 4; ++i)
        *(float4*)(C + (long)(m0 + ty * 4 + i) * CA3C + n0 + tx * 4) =
            make_float4(acc[i][0], acc[i][1], acc[i][2], acc[i][3]);
}

// ---------------- Phase B2: fp64 re-check of near-zero dots (sign safety) ----------
__global__ __launch_bounds__(256) void k_fixup(const float* __restrict__ hippo,
        const float* __restrict__ w, float* __restrict__ dots) {
    long i = (long)blockIdx.x * 256 + threadIdx.x;
    float d = dots[i];
    if (fabsf(d) < 1e-3f) {
        int s = (int)(i / CA3C), c = (int)(i % CA3C);
        const float* hr = hippo + (long)s * NN;
        const float* wr = w + (long)c * NN;
        double acc = 0.0;
        for (int n = 0; n < NN; ++n) acc += (double)hr[n] * (double)wr[n];
        dots[i] = (acc > 0.0) ? 1.0f : -1.0f;   // only the sign is consumed
    }
}

// ---------------- Phase C0: pack pre bits [s][64 words] + per-step popcount --------
__global__ __launch_bounds__(64) void k_packpre(const float* __restrict__ dots,
        unsigned* __restrict__ pre_bits, float* __restrict__ pre_popf) {
    int s = blockIdx.x;
    int lane = threadIdx.x;                    // 0..63 -> word index
    const float* row = dots + (long)s * CA3C + lane * 32;
    unsigned m = 0;
    #pragma unroll
    for (int j = 0; j < 32; ++j) m |= (row[j] > 0.0f ? 1u : 0u) << j;
    pre_bits[s * 64 + lane] = m;
    int pc = __popc(m);
    #pragma unroll
    for (int o = 1; o < 64; o <<= 1) pc += __shfl_xor(pc, o, 64);
    if (lane == 0) pre_popf[s] = (float)pc;
}

// ---------------- Phase C1: pack post bits transposed [r][32 words over steps] -----
__global__ __launch_bounds__(256) void k_packpost(const float* __restrict__ dots,
        unsigned* __restrict__ postT) {
    int r = blockIdx.x * 256 + threadIdx.x;    // 0..2047
    #pragma unroll 1
    for (int wi = 0; wi < 32; ++wi) {
        unsigned m = 0;
        int jmax = (wi == 31) ? 31 : 32;       // steps s = wi*32+j, s <= 1022
        for (int j = 0; j < jmax; ++j) {
            int s = wi * 32 + j;
            m |= (dots[(long)(s + 1) * CA3C + r] > 0.0f ? 1u : 0u) << j;
        }
        postT[r * 32 + wi] = m;
    }
}

// ---------------- DPP-based full-wave (64 lane) sum; result broadcast via lane 63 ---
__device__ __forceinline__ float wave_sum64(float x) {
    #define DPPADD(ctrl, rmask) \
        x += __int_as_float(__builtin_amdgcn_update_dpp(0, __float_as_int(x), ctrl, rmask, 0xF, true))
    DPPADD(0xB1, 0xF);    // quad_perm [1,0,3,2]  (xor 1)
    DPPADD(0x4E, 0xF);    // quad_perm [2,3,0,1]  (xor 2)
    DPPADD(0x141, 0xF);   // row_half_mirror      (xor 4)
    DPPADD(0x140, 0xF);   // row_mirror           (xor 8)
    DPPADD(0x142, 0xA);   // row_bcast15 -> rows 1,3
    DPPADD(0x143, 0xC);   // row_bcast31 -> rows 2,3
    #undef DPPADD
    return __int_as_float(__builtin_amdgcn_readlane(__float_as_int(x), 63));
}

// ---------------- Phase D: per-row sequential Hebbian scan (1 wave = 1 row) --------
// W_r = alpha * V_r; nu = ||W_r||^2 tracked incrementally. Renorm is division-free
// and branchless: t = max(nu,1); alpha *= rsqrt(t); inv_alpha *= sqrt(t);
// nu = min(nu,1) -- exact no-op when nu <= 1 (rsqrt(1)=sqrt(1)=1).
// __launch_bounds__(256, 2): VGPR cap 256 so V[32] stays in registers
// (R1/R2 allocated only 40-48 VGPRs -> V spilled to scratch -> L2-latency-bound).
__global__ __launch_bounds__(256, 2) void k_scan(const float* __restrict__ W0,
        const unsigned* __restrict__ pre_bits, const float* __restrict__ pre_popf,
        const unsigned* __restrict__ postT, float* __restrict__ Wout) {
    int r = (blockIdx.x * 256 + threadIdx.x) >> 6;   // wave id = row
    int lane = threadIdx.x & 63;
    const float* src = W0 + (long)r * CA3C + lane * 32;
    float V[32];
    #pragma unroll
    for (int j = 0; j < 32; ++j) V[j] = src[j];
    float p0 = 0.f, p1 = 0.f, p2 = 0.f, p3 = 0.f;
    #pragma unroll
    for (int j = 0; j < 32; j += 4) {
        p0 = fmaf(V[j+0], V[j+0], p0);
        p1 = fmaf(V[j+1], V[j+1], p1);
        p2 = fmaf(V[j+2], V[j+2], p2);
        p3 = fmaf(V[j+3], V[j+3], p3);
    }
    float nu = wave_sum64((p0 + p1) + (p2 + p3));
    float alpha = 1.f, inv_alpha = 1.f;
    {
        float t = fmaxf(nu, 1.f);
        alpha *= rsqrtf(t); inv_alpha *= sqrtf(t); nu = fminf(nu, 1.f);
    }

    unsigned pw = 0;
    unsigned mnext = pre_bits[lane];                 // prefetch step 0
    float popnext = pre_popf[0];
    for (int s = 0; s < SEQ - 1; ++s) {
        unsigned m = mnext;
        float pop = popnext;
        if (s + 1 < SEQ - 1) {
            mnext = pre_bits[(s + 1) * 64 + lane];
            popnext = pre_popf[s + 1];
        }
        if ((s & 31) == 0) pw = __builtin_amdgcn_readfirstlane(postT[r * 32 + (s >> 5)]);
        if ((pw >> (s & 31)) & 1u) {
            float c = LRC * inv_alpha;
            float d0 = 0.f, d1 = 0.f, d2 = 0.f, d3 = 0.f;
            #pragma unroll
            for (int j = 0; j < 32; j += 4) {
                float f0 = (float)((m >> (j + 0)) & 1u);
                float f1 = (float)((m >> (j + 1)) & 1u);
                float f2 = (float)((m >> (j + 2)) & 1u);
                float f3 = (float)((m >> (j + 3)) & 1u);
                d0 = fmaf(f0, V[j+0], d0); V[j+0] = fmaf(f0, c, V[j+0]);
                d1 = fmaf(f1, V[j+1], d1); V[j+1] = fmaf(f1, c, V[j+1]);
                d2 = fmaf(f2, V[j+2], d2); V[j+2] = fmaf(f2, c, V[j+2]);
                d3 = fmaf(f3, V[j+3], d3); V[j+3] = fmaf(f3, c, V[j+3]);
            }
            float dot = wave_sum64((d0 + d1) + (d2 + d3));
            nu = fmaf(2.f * LRC, alpha * dot, fmaf(LRC * LRC, pop, nu));
            float t = fmaxf(nu, 1.f);
            alpha *= rsqrtf(t);
            inv_alpha *= sqrtf(t);
            nu = fminf(nu, 1.f);
            if (alpha < 1e-6f) {                     // re-materialize to avoid drift/overflow
                #pragma unroll
                for (int j = 0; j < 32; ++j) V[j] *= alpha;
                alpha = 1.f; inv_alpha = 1.f;
            }
        }
    }
    float* dst = Wout + (long)r * CA3C + lane * 32;
    #pragma unroll
    for (int j = 0; j < 32; ++j) dst[j] = alpha * V[j];
}

extern "C" void kernel_launch(void* const* d_in, const int* in_sizes, int n_in,
                              void* d_out, int out_size, void* d_ws, size_t ws_size,
                              hipStream_t stream) {
    const int*   tok     = (const int*)d_in[0];
    const float* sdr     = (const float*)d_in[1];
    const float* pos     = (const float*)d_in[2];
    const float* w_hippo = (const float*)d_in[3];
    const float* assoc   = (const float*)d_in[4];
    float* out = (float*)d_out;

    char* ws = (char*)d_ws;
    float*    hippo    = (float*)(ws);                     // 8 MB
    float*    dots     = (float*)(ws + 8388608);           // 8 MB
    unsigned* pre_bits = (unsigned*)(ws + 16777216);       // 256 KB
    unsigned* postT    = (unsigned*)(ws + 17039360);       // 256 KB
    float*    pre_popf = (float*)(ws + 17301504);          // 4 KB

    k_hippo   <<<dim3(SEQ, 2),            256, 0, stream>>>(tok, sdr, pos, hippo);
    k_gemm    <<<dim3(CA3C/64, SEQ/64),   256, 0, stream>>>(hippo, w_hippo, dots);
    k_fixup   <<<dim3((SEQ*CA3C)/256),    256, 0, stream>>>(hippo, w_hippo, dots);
    k_packpre <<<dim3(SEQ),                64, 0, stream>>>(dots, pre_bits, pre_popf);
    k_packpost<<<dim3(CA3C/256),          256, 0, stream>>>(dots, postT);
    k_scan    <<<dim3(CA3C*64/256),       256, 0, stream>>>(assoc, pre_bits, pre_popf, postT, out);
}

// Round 4
// 990.922 us; speedup vs baseline: 1.2929x; 1.2700x over previous
//
#include <hip/hip_runtime.h>
#include <hip/hip_bf16.h>

#define NT    10
#define NN    2048   // n_neurons
#define CA3C  2048
#define SEQ   1024
#define SPARS 0.05f
#define LRC   0.01f

typedef float    f32x4 __attribute__((ext_vector_type(4)));
typedef unsigned u32x4 __attribute__((ext_vector_type(4)));

// ---------------- Phase A: hippo_input[s][n] = sum_t tok_spike*(1+0.5*pos_spike) ----
__global__ __launch_bounds__(256) void k_hippo(const int* __restrict__ tok,
        const float* __restrict__ sdr, const float* __restrict__ pos,
        float* __restrict__ hippo) {
    int s = blockIdx.x;
    int n = (blockIdx.y * 256 + threadIdx.x) * 4;
    const float* sp = sdr + (long)tok[s] * (NT * NN) + n;
    const float* pp = pos + (long)s * (NT * NN) + n;
    float a0 = 0.f, a1 = 0.f, a2 = 0.f, a3 = 0.f;
    #pragma unroll
    for (int t = 0; t < NT; ++t) {
        float4 sv = *(const float4*)(sp + t * NN);
        float4 pv = *(const float4*)(pp + t * NN);
        if (sv.x < SPARS) a0 += (pv.x < SPARS) ? 1.5f : 1.0f;
        if (sv.y < SPARS) a1 += (pv.y < SPARS) ? 1.5f : 1.0f;
        if (sv.z < SPARS) a2 += (pv.z < SPARS) ? 1.5f : 1.0f;
        if (sv.w < SPARS) a3 += (pv.w < SPARS) ? 1.5f : 1.0f;
    }
    *(float4*)(hippo + (long)s * NN + n) = make_float4(a0, a1, a2, a3);
}

// ---------------- Phase B: dots[s][c] = hippo[s] . w_hippo[c]  (fp32 tiled GEMM) ----
__global__ __launch_bounds__(256) void k_gemm(const float* __restrict__ A,
        const float* __restrict__ B, float* __restrict__ C) {
    __shared__ float As[32][68];   // [k][m], padded row stride 68 (16B aligned)
    __shared__ float Bs[32][68];   // [k][n]
    int tid = threadIdx.x;
    int tx = tid & 15, ty = tid >> 4;
    int m0 = blockIdx.y * 64, n0 = blockIdx.x * 64;
    int lr = tid >> 3;            // 0..31
    int lk = (tid & 7) * 4;       // 0..28
    float acc[4][4] = {};
    for (int k0 = 0; k0 < NN; k0 += 32) {
        float4 a0 = *(const float4*)(A + (m0 + lr) * NN + k0 + lk);
        float4 a1 = *(const float4*)(A + (m0 + lr + 32) * NN + k0 + lk);
        float4 b0 = *(const float4*)(B + (n0 + lr) * NN + k0 + lk);
        float4 b1 = *(const float4*)(B + (n0 + lr + 32) * NN + k0 + lk);
        __syncthreads();
        As[lk + 0][lr] = a0.x; As[lk + 1][lr] = a0.y; As[lk + 2][lr] = a0.z; As[lk + 3][lr] = a0.w;
        As[lk + 0][lr + 32] = a1.x; As[lk + 1][lr + 32] = a1.y; As[lk + 2][lr + 32] = a1.z; As[lk + 3][lr + 32] = a1.w;
        Bs[lk + 0][lr] = b0.x; Bs[lk + 1][lr] = b0.y; Bs[lk + 2][lr] = b0.z; Bs[lk + 3][lr] = b0.w;
        Bs[lk + 0][lr + 32] = b1.x; Bs[lk + 1][lr + 32] = b1.y; Bs[lk + 2][lr + 32] = b1.z; Bs[lk + 3][lr + 32] = b1.w;
        __syncthreads();
        #pragma unroll
        for (int k = 0; k < 32; ++k) {
            float4 av = *(const float4*)&As[k][ty * 4];
            float4 bv = *(const float4*)&Bs[k][tx * 4];
            float aa[4] = {av.x, av.y, av.z, av.w};
            float bb[4] = {bv.x, bv.y, bv.z, bv.w};
            #pragma unroll
            for (int i = 0; i < 4; ++i)
                #pragma unroll
                for (int j = 0; j < 4; ++j)
                    acc[i][j] = fmaf(aa[i], bb[j], acc[i][j]);
        }
    }
    #pragma unroll
    for (int i = 0; i < 4; ++i)
        *(float4*)(C + (long)(m0 + ty * 4 + i) * CA3C + n0 + tx * 4) =
            make_float4(acc[i][0], acc[i][1], acc[i][2], acc[i][3]);
}

// ---------------- Phase B2: fp64 re-check of near-zero dots (sign safety) ----------
__global__ __launch_bounds__(256) void k_fixup(const float* __restrict__ hippo,
        const float* __restrict__ w, float* __restrict__ dots) {
    long i = (long)blockIdx.x * 256 + threadIdx.x;
    float d = dots[i];
    if (fabsf(d) < 1e-3f) {
        int s = (int)(i / CA3C), c = (int)(i % CA3C);
        const float* hr = hippo + (long)s * NN;
        const float* wr = w + (long)c * NN;
        double acc = 0.0;
        for (int n = 0; n < NN; ++n) acc += (double)hr[n] * (double)wr[n];
        dots[i] = (acc > 0.0) ? 1.0f : -1.0f;   // only the sign is consumed
    }
}

// ---------------- Phase C0: pack pre bits TRANSPOSED preT[w][1024] + popcounts -----
__global__ __launch_bounds__(64) void k_packpre(const float* __restrict__ dots,
        unsigned* __restrict__ preT, float* __restrict__ popf) {
    int s = blockIdx.x;                        // 0..1023 (step index)
    int w = threadIdx.x;                       // 0..63 -> word index
    const float* row = dots + (long)s * CA3C + w * 32;
    unsigned m = 0;
    #pragma unroll
    for (int j = 0; j < 32; ++j) m |= (row[j] > 0.0f ? 1u : 0u) << j;
    preT[w * SEQ + s] = m;                     // transposed: 4 consecutive steps -> uint4
    int pc = __popc(m);
    #pragma unroll
    for (int o = 1; o < 64; o <<= 1) pc += __shfl_xor(pc, o, 64);
    if (w == 0) popf[s] = (float)pc;
}

// ---------------- Phase C1: pack post bits transposed [r][32 words over steps] -----
__global__ __launch_bounds__(256) void k_packpost(const float* __restrict__ dots,
        unsigned* __restrict__ postT) {
    int r = blockIdx.x * 256 + threadIdx.x;    // 0..2047
    #pragma unroll 1
    for (int wi = 0; wi < 32; ++wi) {
        unsigned m = 0;
        int jmax = (wi == 31) ? 31 : 32;       // steps s = wi*32+j, s <= 1022
        for (int j = 0; j < jmax; ++j) {
            int s = wi * 32 + j;
            m |= (dots[(long)(s + 1) * CA3C + r] > 0.0f ? 1u : 0u) << j;
        }
        postT[r * 32 + wi] = m;
    }
}

// ---------------- DPP-based full-wave (64 lane) sum; result broadcast via lane 63 ---
__device__ __forceinline__ float wave_sum64(float x) {
    #define DPPADD(ctrl, rmask) \
        x += __int_as_float(__builtin_amdgcn_update_dpp(0, __float_as_int(x), ctrl, rmask, 0xF, true))
    DPPADD(0xB1, 0xF);    // quad_perm [1,0,3,2]  (xor 1)
    DPPADD(0x4E, 0xF);    // quad_perm [2,3,0,1]  (xor 2)
    DPPADD(0x141, 0xF);   // row_half_mirror      (xor 4)
    DPPADD(0x140, 0xF);   // row_mirror           (xor 8)
    DPPADD(0x142, 0xA);   // row_bcast15 -> rows 1,3
    DPPADD(0x143, 0xC);   // row_bcast31 -> rows 2,3
    #undef DPPADD
    return __int_as_float(__builtin_amdgcn_readlane(__float_as_int(x), 63));
}

// ---------------- Phase D: per-row sequential Hebbian scan (1 wave = 1 row) --------
// W_r = alpha * V_r; nu = ||W_r||^2 tracked incrementally; renorm division-free and
// branchless. V held in 8 NAMED ext-vector f32x4 values (no array -> nothing the
// compiler can demote to scratch; R1-R3 allocated 40-48 VGPRs => V[32] array lived
// in scratch and the loop was L2-latency/BW-bound). preT is step-transposed so one
// uint4 load feeds 4 steps (serial load->use chain 1023 -> 256 links).
#define HEB_GROUP(G, VV) { \
    f32x4 fv; \
    fv.x = (float)((m >> (4*G + 0)) & 1u); \
    fv.y = (float)((m >> (4*G + 1)) & 1u); \
    fv.z = (float)((m >> (4*G + 2)) & 1u); \
    fv.w = (float)((m >> (4*G + 3)) & 1u); \
    d += fv * VV; \
    VV += fv * cv; }

#define HEB_STEP(B) { \
    if ((pw >> (((sg & 7) << 2) + B)) & 1u) { \
        unsigned m = mg[B]; \
        float c = LRC * inv_alpha; \
        f32x4 cv = {c, c, c, c}; \
        f32x4 d = {0.f, 0.f, 0.f, 0.f}; \
        HEB_GROUP(0, V0) HEB_GROUP(1, V1) HEB_GROUP(2, V2) HEB_GROUP(3, V3) \
        HEB_GROUP(4, V4) HEB_GROUP(5, V5) HEB_GROUP(6, V6) HEB_GROUP(7, V7) \
        float dot = wave_sum64((d.x + d.y) + (d.z + d.w)); \
        nu = fmaf(2.f * LRC, alpha * dot, fmaf(LRC * LRC, popg[B], nu)); \
        float t = fmaxf(nu, 1.f); \
        alpha *= rsqrtf(t); inv_alpha *= sqrtf(t); nu = fminf(nu, 1.f); \
        if (alpha < 1e-6f) { \
            f32x4 av = {alpha, alpha, alpha, alpha}; \
            V0 *= av; V1 *= av; V2 *= av; V3 *= av; \
            V4 *= av; V5 *= av; V6 *= av; V7 *= av; \
            alpha = 1.f; inv_alpha = 1.f; \
        } \
    } }

__global__ __launch_bounds__(256, 2) void k_scan(const float* __restrict__ W0,
        const unsigned* __restrict__ preT, const float* __restrict__ popf,
        const unsigned* __restrict__ postT, float* __restrict__ Wout) {
    int r = (blockIdx.x * 256 + threadIdx.x) >> 6;   // wave id = row
    int lane = threadIdx.x & 63;
    const float* src = W0 + (long)r * CA3C + lane * 32;
    f32x4 V0 = *(const f32x4*)(src +  0), V1 = *(const f32x4*)(src +  4);
    f32x4 V2 = *(const f32x4*)(src +  8), V3 = *(const f32x4*)(src + 12);
    f32x4 V4 = *(const f32x4*)(src + 16), V5 = *(const f32x4*)(src + 20);
    f32x4 V6 = *(const f32x4*)(src + 24), V7 = *(const f32x4*)(src + 28);
    f32x4 p = V0 * V0;
    p += V1 * V1; p += V2 * V2; p += V3 * V3;
    p += V4 * V4; p += V5 * V5; p += V6 * V6; p += V7 * V7;
    float nu = wave_sum64((p.x + p.y) + (p.z + p.w));
    float alpha = 1.f, inv_alpha = 1.f;
    {
        float t = fmaxf(nu, 1.f);
        alpha *= rsqrtf(t); inv_alpha *= sqrtf(t); nu = fminf(nu, 1.f);
    }

    const u32x4* pT4 = (const u32x4*)(preT + (long)lane * SEQ);  // 4 steps per load
    const f32x4* pF4 = (const f32x4*)popf;
    u32x4 mg_n  = pT4[0];
    f32x4 pop_n = pF4[0];
    unsigned pw = 0;
    for (int sg = 0; sg < SEQ / 4; ++sg) {           // 256 groups x 4 steps
        u32x4 mg   = mg_n;
        f32x4 popg = pop_n;
        if (sg + 1 < SEQ / 4) { mg_n = pT4[sg + 1]; pop_n = pF4[sg + 1]; }
        if ((sg & 7) == 0) pw = __builtin_amdgcn_readfirstlane(postT[r * 32 + (sg >> 3)]);
        HEB_STEP(0) HEB_STEP(1) HEB_STEP(2) HEB_STEP(3)
        // step 1023 (sg=255,B=3) is always inactive: postT word 31 bit 31 == 0
    }
    float* dst = Wout + (long)r * CA3C + lane * 32;
    f32x4 av = {alpha, alpha, alpha, alpha};
    *(f32x4*)(dst +  0) = V0 * av; *(f32x4*)(dst +  4) = V1 * av;
    *(f32x4*)(dst +  8) = V2 * av; *(f32x4*)(dst + 12) = V3 * av;
    *(f32x4*)(dst + 16) = V4 * av; *(f32x4*)(dst + 20) = V5 * av;
    *(f32x4*)(dst + 24) = V6 * av; *(f32x4*)(dst + 28) = V7 * av;
}

extern "C" void kernel_launch(void* const* d_in, const int* in_sizes, int n_in,
                              void* d_out, int out_size, void* d_ws, size_t ws_size,
                              hipStream_t stream) {
    const int*   tok     = (const int*)d_in[0];
    const float* sdr     = (const float*)d_in[1];
    const float* pos     = (const float*)d_in[2];
    const float* w_hippo = (const float*)d_in[3];
    const float* assoc   = (const float*)d_in[4];
    float* out = (float*)d_out;

    char* ws = (char*)d_ws;
    float*    hippo = (float*)(ws);                        // 8 MB
    float*    dots  = (float*)(ws + 8388608);              // 8 MB
    unsigned* preT  = (unsigned*)(ws + 16777216);          // 256 KB (transposed bits)
    unsigned* postT = (unsigned*)(ws + 17039360);          // 256 KB
    float*    popf  = (float*)(ws + 17301504);             // 4 KB

    k_hippo   <<<dim3(SEQ, 2),            256, 0, stream>>>(tok, sdr, pos, hippo);
    k_gemm    <<<dim3(CA3C/64, SEQ/64),   256, 0, stream>>>(hippo, w_hippo, dots);
    k_fixup   <<<dim3((SEQ*CA3C)/256),    256, 0, stream>>>(hippo, w_hippo, dots);
    k_packpre <<<dim3(SEQ),                64, 0, stream>>>(dots, preT, popf);
    k_packpost<<<dim3(CA3C/256),          256, 0, stream>>>(dots, postT);
    k_scan    <<<dim3(CA3C*64/256),       256, 0, stream>>>(assoc, preT, popf, postT, out);
}